// Round 2
// baseline (635.799 us; speedup 1.0000x reference)
//
#include <hip/hip_runtime.h>
#include <math.h>

#define BB 8192
#define TT 60
#define NU 100
#define NI 7

typedef float v2f __attribute__((ext_vector_type(2)));
typedef float v4f __attribute__((ext_vector_type(4)));

// K-SPLIT STRUCTURE (round 2):
// block = 256 thr = 4 waves = 2 trials x 2 k-halves. Wave (trial, kh) holds,
// for lane l's unit pair (2l, 2l+1), only k in [kh*50, kh*50+50): 50 v2f =
// 100 VGPRs (was 200). Target ~140 regs/wave -> 3 waves/SIMD (512-reg pool)
// instead of 2 — occupancy was the round-1 limiter (VALUBusy 48%, stalls
// unfilled). Each wave computes a partial dot for ALL 100 units over its
// k-half; partials meet via a double-buffered LDS buffer + ONE barrier/step.
// Both waves duplicate the cheap scalar tail (z, DPP, state) — no extra
// serial dependency; only kh==0 writes outputs.
#define FOR25(M) M(0) M(1) M(2) M(3) M(4) M(5) M(6) M(7) M(8) M(9) \
  M(10) M(11) M(12) M(13) M(14) M(15) M(16) M(17) M(18) M(19) \
  M(20) M(21) M(22) M(23) M(24)

// v4f groups: M(j2, ja, jb) with ja=2*j2, jb=2*j2+1 (local k-pair indices)
#define FOR12P(M) M(0,0,1) M(1,2,3) M(2,4,5) M(3,6,7) M(4,8,9) M(5,10,11) \
  M(6,12,13) M(7,14,15) M(8,16,17) M(9,18,19) M(10,20,21) M(11,22,23)

// k-half weight decls: contiguous v2f loads from each owned row
#define DECLW(j) \
  const v2f wa_##j = rowA[j]; \
  const v2f wb_##j = rowB[j];

// MAC over one v4f of broadcast y (4 local k values): 4 independent chains
#define MAC2(j2, ja, jb) { \
  const v4f y4 = Yv[j2]; \
  const v2f ylo = { y4.x, y4.y }; \
  const v2f yhi = { y4.z, y4.w }; \
  accA0 += ylo * wa_##ja; \
  accB0 += ylo * wb_##ja; \
  accA1 += yhi * wa_##jb; \
  accB1 += yhi * wb_##jb; }

#define RL(v,l) __int_as_float(__builtin_amdgcn_readlane(__float_as_int(v), l))

// DPP add-reduce step: part += dpp_move(part, ctrl) (pure VALU, no LDS)
#define DPPADD(ctrl, rmask) { \
  const int _t = __builtin_amdgcn_update_dpp(0, __float_as_int(part), (ctrl), (rmask), 0xf, false); \
  part += __int_as_float(_t); }

__global__ __launch_bounds__(256, 3)
void drr_kernel(const float* __restrict__ y0,
                const float* __restrict__ noise,
                const int*   __restrict__ stim_idx,
                const int*   __restrict__ rew_idx,
                const int*   __restrict__ instr_in,
                const float* __restrict__ W_in_raw,
                const float* __restrict__ W_rec,
                const float* __restrict__ b_rec,
                const float* __restrict__ w_out,
                const float* __restrict__ b_out,
                float* __restrict__ out)
{
    const int lane  = threadIdx.x & 63;
    const int wid   = threadIdx.x >> 6;
    const int kh    = wid & 1;                 // k-half of this wave
    const int trial = blockIdx.x * 2 + (wid >> 1);

    const bool act = (lane < 50);              // active unit-pair lanes
    const int  la  = act ? lane : 49;          // clamped
    const int  ua  = 2 * la;                   // first unit
    const int  uao = ua * NU;

    // per-trial scalars (wave-uniform)
    const int  stim    = stim_idx[trial];
    const int  rew     = rew_idx[trial];
    const bool is_rew  = (stim == rew);
    const bool instr_b = (instr_in[trial] > 0);

    // k-half weight registers: rows ua, ua+1, columns [kh*50, kh*50+50)
    const v2f* rowA = (const v2f*)(W_rec + uao + kh * 50);
    const v2f* rowB = (const v2f*)(W_rec + uao + NU + kh * 50);
    FOR25(DECLW)

    // W_in columns (abs applied), packed per unit pair
    const v2f wi6 = { fabsf(W_in_raw[ua * NI + 6]),    fabsf(W_in_raw[(ua+1) * NI + 6]) };
    const v2f wis = { fabsf(W_in_raw[ua * NI + stim]), fabsf(W_in_raw[(ua+1) * NI + stim]) };
    const v2f wr  = { fabsf(W_in_raw[ua * NI + 4]),    fabsf(W_in_raw[(ua+1) * NI + 4]) };
    const v2f wl  = { fabsf(W_in_raw[ua * NI + 5]),    fabsf(W_in_raw[(ua+1) * NI + 5]) };
    const v2f br  = { b_rec[ua], b_rec[ua + 1] };
    const v2f wo  = act ? (v2f){ w_out[ua], w_out[ua + 1] } : (v2f){ 0.0f, 0.0f };
    const float bo = b_out[0];

    const v2f* y0v = (const v2f*)(y0 + trial * NU);
    v2f yy = y0v[la];

    const float NS = 0.09486832980505138f; // 0.15 * sqrt(2*0.2)

    bool licked = false, instr_fired = false;
    int  lick_t = TT + 1;

    const float* nbase = noise + trial * (TT * NU);
    v2f en = ((const v2f*)nbase)[la];          // t=0 prefetch (8B load)

    // y broadcast strips (per wave, rotated so own k-half is v4f-aligned at 0)
    __shared__ v4f lds_y[4][32];
    // partial-dot exchange, double-buffered by t parity
    __shared__ v2f lds_p[2][4][64];

    v2f*       yw = (v2f*)&lds_y[wid][0];
    const v4f* Yv = &lds_y[wid][0];
    const v2f* Yt = (const v2f*)&lds_y[wid][0];
    const int  ypos = (la + kh * 25) % 50;     // publish slot: rotate by kh*50 floats

    // output section pointers (flat tuple order)
    float* uout  = out;                        // B*T*7
    float* tout  = out  + BB * TT * NI;        // B*T
    float* rout  = tout + BB * TT;             // B*T
    float* lout  = rout + BB * TT;             // B
    float* dout  = lout + BB;                  // B
    float* zout  = dout + BB;                  // B*T
    float* yfout = zout + BB * TT;             // B*100

    for (int t = 0; t < TT; ++t) {
        // publish current y (rotated): strip floats [0,50) = own k-half.
        // Wave-local write->read; compiler orders via lgkmcnt, no barrier.
        yw[ypos] = yy;

        const v2f e = en;
        if (t < TT - 1)
            en = ((const v2f*)(nbase + (t + 1) * NU))[la];

        const float sm = (t >= 10 && t < 15) ? 1.0f : 0.0f;  // stim_mask
        const float rm = (t >= 20 && t < 35) ? 1.0f : 0.0f;  // resp_mask

        // reward routing (state from previous step), wave-uniform,
        // duplicated identically in both k-half waves
        const bool delivered    = instr_fired || (licked && is_rew);
        const bool fire         = instr_b && !delivered && (t == 30);
        instr_fired             = instr_fired || fire;
        const bool instr_active = instr_fired && (t >= 30) && (t < 35);
        const bool lick_dyn     = licked && (t > lick_t) && (t < lick_t + 5);
        const float a_rew  = (instr_active ? 1.0f : 0.0f) + ((lick_dyn && is_rew) ? 1.0f : 0.0f);
        const float a_lick = lick_dyn ? 1.0f : 0.0f;

        // per-unit base (unit-packed v2f)
        const v2f base = br + rm * wi6 + sm * wis + a_rew * wr + a_lick * wl + NS * e;

        v2f accA0 = { 0.0f, 0.0f };
        v2f accA1 = { 0.0f, 0.0f };
        v2f accB0 = { 0.0f, 0.0f };
        v2f accB1 = { 0.0f, 0.0f };

        FOR12P(MAC2)                           // 12 uniform ds_read_b128, 48 k's
        {                                      // tail: local k-pair 24
            const v2f yt = Yt[24];
            accA1 += yt * wa_24;
            accB1 += yt * wb_24;
        }

        const v2f sA = accA0 + accA1;
        const v2f sB = accB0 + accB1;
        const v2f partial = { sA.x + sA.y, sB.x + sB.y };

        // exchange partials with partner k-half wave (double-buffered)
        lds_p[t & 1][wid][la] = partial;
        __syncthreads();
        const v2f other = lds_p[t & 1][wid ^ 1][la];

        const v2f pre  = base + partial + other;
        const v2f prer = { fmaxf(pre.x, 0.0f), fmaxf(pre.y, 0.0f) };
        yy = 0.8f * yy + 0.2f * prer;

        // z = sigmoid(y . w_out + b_out) — DPP wave64 reduction (duplicated
        // in both waves; identical arithmetic -> identical state)
        float part = yy.x * wo.x + yy.y * wo.y;
        DPPADD(0x111, 0xf)   // row_shr:1
        DPPADD(0x112, 0xf)   // row_shr:2
        DPPADD(0x114, 0xf)   // row_shr:4
        DPPADD(0x118, 0xf)   // row_shr:8
        DPPADD(0x142, 0xa)   // row_bcast:15 -> rows 1,3
        DPPADD(0x143, 0xc)   // row_bcast:31 -> rows 2,3
        const float x = RL(part, 63) + bo;     // uniform via SGPR
        const float z = 1.0f / (1.0f + expf(-x));

        const bool in_resp = (t >= 20) && (t < 35);
        const bool trig    = in_resp && !licked && (z > 0.5f);
        if (trig) lick_t = t;          // wave-uniform
        licked = licked || trig;
        const bool u5 = licked && (t >= lick_t) && (t < lick_t + 5);
        const bool u4 = instr_active || (u5 && is_rew);

        // per-step outputs — kh==0 wave only
        if (kh == 0) {
            const int bt = trial * TT + t;
            if (lane < NI) {
                float uv = 0.0f;
                if (lane == stim) uv = sm;                 // stim in [0,4)
                if (lane == 4)    uv = u4 ? 1.0f : 0.0f;
                if (lane == 5)    uv = u5 ? 1.0f : 0.0f;
                if (lane == 6)    uv = rm;
                uout[bt * NI + lane] = uv;
            } else if (lane == 8) {
                tout[bt] = is_rew ? rm : 0.0f;
            } else if (lane == 9) {
                rout[bt] = rm;
            } else if (lane == 10) {
                zout[bt] = z;
            }
        }
    }

    if (kh == 0) {
        if (lane == 0) {
            lout[trial] = licked ? 1.0f : 0.0f;
            dout[trial] = (instr_fired || (licked && is_rew)) ? 1.0f : 0.0f;
        }
        if (act)
            ((v2f*)(yfout + trial * NU))[la] = yy;   // 8B store, units 2l/2l+1
    }
}

extern "C" void kernel_launch(void* const* d_in, const int* in_sizes, int n_in,
                              void* d_out, int out_size, void* d_ws, size_t ws_size,
                              hipStream_t stream) {
    const float* y0       = (const float*)d_in[0];
    const float* noise    = (const float*)d_in[1];
    const int*   stim     = (const int*)  d_in[2];
    const int*   rew      = (const int*)  d_in[3];
    const int*   instr    = (const int*)  d_in[4];
    const float* W_in_raw = (const float*)d_in[5];
    const float* W_rec    = (const float*)d_in[6];
    const float* b_rec    = (const float*)d_in[7];
    const float* w_out    = (const float*)d_in[8];
    const float* b_out    = (const float*)d_in[9];
    float* out = (float*)d_out;

    drr_kernel<<<BB / 2, 256, 0, stream>>>(y0, noise, stim, rew, instr,
                                           W_in_raw, W_rec, b_rec, w_out, b_out, out);
}